// Round 12
// baseline (35.376 us; speedup 1.0000x reference)
//
#include <hip/hip_runtime.h>
#include <hip/hip_bf16.h>

#define IN_F   4096
#define OUT_F  11008
#define BATCH  32
#define GROUP  128
#define NTILE  32
#define KSPLIT 8
#define GRID_N (OUT_F / NTILE)    // 344
#define OUTSZ  (BATCH * OUT_F)    // 352256

typedef __attribute__((ext_vector_type(8))) short  bf16x8;
typedef __attribute__((ext_vector_type(4))) float  f32x4;
typedef __attribute__((ext_vector_type(4))) int    i32x4;
typedef __attribute__((ext_vector_type(4))) float  float4v;

static __device__ __constant__ float NF4_LEVELS[16] = {
    -1.0f, -0.6961928009986877f, -0.5250730514526367f, -0.39491748809814453f,
    -0.28444138169288635f, -0.18477343022823334f, -0.09105003625154495f, 0.0f,
    0.07958029955625534f, 0.16093020141124725f, 0.24611230194568634f,
    0.33791524171829224f, 0.44070982933044434f, 0.5626170039176941f,
    0.7229568362236023f, 1.0f};

// ---------------------------------------------------------------------------
// Prelude (408 blocks):
//   bid <  64: A-fragment streams in MFMA order:
//     frag[st][kb][lane] (16B) = x[st*16+(lane&15)][kb*32+(lane>>4)*8..+8) bf16
//   bid >= 64: out[b][o] = bias[o]  (base for gemm atomics)
// ---------------------------------------------------------------------------
__global__ void prelude_kernel(const float* __restrict__ x,
                               const float* __restrict__ bias,
                               unsigned short* __restrict__ frag,
                               float* __restrict__ out) {
    const int bid = blockIdx.x, tid = threadIdx.x;
    if (bid < 64) {
        int T  = bid * 256 + tid;
        int st = T >> 13;
        int kb = (T >> 6) & 127;
        int l  = T & 63;
        int row = st * 16 + (l & 15);
        int k0  = kb * 32 + (l >> 4) * 8;
        const float* src = x + (size_t)row * IN_F + k0;
        unsigned w[4];
        #pragma unroll
        for (int e = 0; e < 4; ++e) {
            unsigned lo = __builtin_bit_cast(unsigned short, __float2bfloat16(src[2 * e]));
            unsigned hi = __builtin_bit_cast(unsigned short, __float2bfloat16(src[2 * e + 1]));
            w[e] = lo | (hi << 16);
        }
        i32x4 v = { (int)w[0], (int)w[1], (int)w[2], (int)w[3] };
        *reinterpret_cast<i32x4*>(frag + ((size_t)st * 8192 + kb * 64 + l) * 8) = v;
    } else {
        int t2 = (bid - 64) * 256 + tid;     // [0, 88064)
        int i  = t2 * 4;
        int o  = i % OUT_F;                  // OUT_F%4==0 -> aligned
        float4v b = *reinterpret_cast<const float4v*>(bias + o);
        *reinterpret_cast<float4v*>(out + i) = b;
    }
}

// ---------------------------------------------------------------------------
// Main: grid (344, 8) = 2752 blocks, 256 thr (4 waves), ~6 blocks/CU.
// Block = 32 out-rows x 512 k (ONE unit). Wave w owns k-slice
// [by*512 + w*128, +128) = exactly one scale group; covers both 16-row strips
// and both batch halves: 16 MFMA/wave. No K-accumulate chain: result = sc * t.
//
// Staging: wave w stages rows w*8..+7; one row = 256 int32 = one contiguous
//   1KB wave-load (j = lane covers k [8j, 8j+8)); compact 4 int32 -> 1 dword.
//   Store at (row*64 + p(j)) ^ ((row&7)<<2), p(j)=(j&0x30)|((j&3)<<2)|((j>>2)&3)
//   -> reader ds_read_b128 at (row*64 + w*16 + g*4) ^ ((row&7)<<2) gives
//   k-steps t=0..3 (j = w*16 + t*4 + g).  Writes 2-way banks, reads 2-way (free).
// Epilogue: cross-wave (K) reduce in aliased LDS, unsafeAtomicAdd (8 writers).
// ---------------------------------------------------------------------------
__global__ __launch_bounds__(256, 6) void nf4_gemm_kernel(
        const int* __restrict__ packed,
        const float* __restrict__ scales,
        const unsigned short* __restrict__ frag,
        float* __restrict__ out)
{
    __shared__ unsigned tabu[256];   // byte -> packed bf16 level pair
    __shared__ float    slds[128];   // [wave][32 rows] scales for this k-slice
    __shared__ unsigned lds[4096];   // 16KB: codes in [0,2048); red alias (full)

    const int tid  = threadIdx.x;
    const int wave = tid >> 6;
    const int lane = tid & 63;
    const int col  = lane & 15;
    const int g    = lane >> 4;

    {
        unsigned lo = __builtin_bit_cast(unsigned short, __float2bfloat16(NF4_LEVELS[tid & 15]));
        unsigned hi = __builtin_bit_cast(unsigned short, __float2bfloat16(NF4_LEVELS[(tid >> 4) & 15]));
        tabu[tid] = lo | (hi << 16);
    }

    const int n0 = blockIdx.x * NTILE;
    const int by = blockIdx.y;               // k-slice 0..7

    // scales: wave w needs group by*4+w for rows n0..n0+31 (512B total)
    if (tid < 128) {
        int w = tid >> 5, r = tid & 31;
        slds[w * 32 + r] = scales[(size_t)(n0 + r) * 32 + by * 4 + w];
    }

    const int dperm = (lane & 0x30) | ((lane & 3) << 2) | ((lane >> 2) & 3);

    // ---- stage loads: 8 rows/wave, contiguous 1KB each ----
    i32x4 sr[8];
    #pragma unroll
    for (int ii = 0; ii < 8; ++ii) {
        int row = wave * 8 + ii;
        sr[ii] = *reinterpret_cast<const i32x4*>(
            packed + (size_t)(n0 + row) * (IN_F / 2) + by * 256 + lane * 4);
    }

    // ---- A fragments (issued while staging loads in flight; L2-resident) ----
    const unsigned short* f0 = frag;
    const unsigned short* f1 = frag + 65536;
    bf16x8 A0[4], A1[4];
    #pragma unroll
    for (int t = 0; t < 4; ++t) {
        int kb = by * 16 + wave * 4 + t;
        A0[t] = *reinterpret_cast<const bf16x8*>(f0 + ((size_t)kb * 64 + lane) * 8);
        A1[t] = *reinterpret_cast<const bf16x8*>(f1 + ((size_t)kb * 64 + lane) * 8);
    }

    // ---- compact + swizzled write ----
    #pragma unroll
    for (int ii = 0; ii < 8; ++ii) {
        int row = wave * 8 + ii;
        unsigned v = ((unsigned)(sr[ii][0] & 255))
                   | ((unsigned)(sr[ii][1] & 255) << 8)
                   | ((unsigned)(sr[ii][2] & 255) << 16)
                   | ((unsigned)(sr[ii][3] & 255) << 24);
        lds[(row * 64 + dperm) ^ ((row & 7) << 2)] = v;
    }
    __syncthreads();

    // ---- compute: 2 strips x 2 batch halves x 4 k-steps ----
    i32x4 cd[2];
    #pragma unroll
    for (int st = 0; st < 2; ++st) {
        int row = st * 16 + col;
        cd[st] = *reinterpret_cast<const i32x4*>(
            &lds[(row * 64 + wave * 16 + g * 4) ^ ((row & 7) << 2)]);
    }

    f32x4 t0[2], t1[2];
    #pragma unroll
    for (int st = 0; st < 2; ++st) {
        t0[st] = (f32x4){0.f,0.f,0.f,0.f};
        t1[st] = (f32x4){0.f,0.f,0.f,0.f};
    }

    #pragma unroll
    for (int t = 0; t < 4; ++t) {
        #pragma unroll
        for (int st = 0; st < 2; ++st) {
            unsigned code = (unsigned)cd[st][t];
            i32x4 bu;                        // bfrag once, both batch halves
            bu[0] = (int)tabu[code & 255u];
            bu[1] = (int)tabu[(code >> 8) & 255u];
            bu[2] = (int)tabu[(code >> 16) & 255u];
            bu[3] = (int)tabu[code >> 24];
            bf16x8 bf = __builtin_bit_cast(bf16x8, bu);
            t0[st] = __builtin_amdgcn_mfma_f32_16x16x32_bf16(A0[t], bf, t0[st], 0, 0, 0);
            t1[st] = __builtin_amdgcn_mfma_f32_16x16x32_bf16(A1[t], bf, t1[st], 0, 0, 0);
        }
    }

    float sc[2];
    sc[0] = slds[wave * 32 + col];
    sc[1] = slds[wave * 32 + 16 + col];

    __syncthreads();                         // codes dead; red alias safe

    // ---- cross-wave (K) reduce: red[w][st*2+h][j][lane] ----
    float* red = (float*)lds;
    #pragma unroll
    for (int st = 0; st < 2; ++st)
        #pragma unroll
        for (int j = 0; j < 4; ++j) {
            red[wave * 1024 + (st * 2 + 0) * 256 + j * 64 + lane] = sc[st] * t0[st][j];
            red[wave * 1024 + (st * 2 + 1) * 256 + j * 64 + lane] = sc[st] * t1[st][j];
        }
    __syncthreads();

    // ---- epilogue: 1024 outputs, 4/thread, coalesced 128B atomics ----
    // D layout: batch b = h*16 + g*4 + j, out-col = st*16 + c
    #pragma unroll
    for (int p = 0; p < 4; ++p) {
        int idx = p * 256 + tid;             // [0,1024)
        int o   = idx & 31;                  // out-feature local
        int b   = idx >> 5;                  // batch row
        int st  = o >> 4;
        int c   = o & 15;
        int h   = b >> 4;
        int r   = b & 15;
        int j   = r & 3;
        int g2  = r >> 2;
        int slot = (st * 2 + h) * 256 + j * 64 + g2 * 16 + c;
        float s = red[slot] + red[1024 + slot] + red[2048 + slot] + red[3072 + slot];
        unsafeAtomicAdd(out + (size_t)b * OUT_F + n0 + o, s);
    }
}

// ---------------------------------------------------------------------------
extern "C" void kernel_launch(void* const* d_in, const int* in_sizes, int n_in,
                              void* d_out, int out_size, void* d_ws, size_t ws_size,
                              hipStream_t stream) {
    const float* x      = (const float*)d_in[0];
    const int*   packed = (const int*)d_in[1];
    const float* scales = (const float*)d_in[2];
    const float* bias   = (const float*)d_in[3];
    float* out = (float*)d_out;

    unsigned short* frag = (unsigned short*)d_ws;   // 256 KB

    prelude_kernel<<<408, 256, 0, stream>>>(x, bias, frag, out);
    nf4_gemm_kernel<<<dim3(GRID_N, KSPLIT), 256, 0, stream>>>(packed, scales, frag, out);
}

// Round 13
// 28.023 us; speedup vs baseline: 1.2624x; 1.2624x over previous
//
#include <hip/hip_runtime.h>
#include <hip/hip_bf16.h>

#define IN_F   4096
#define OUT_F  11008
#define BATCH  32
#define NTILE  16
#define GRID_N (OUT_F / NTILE)    // 688

typedef __attribute__((ext_vector_type(8))) short  bf16x8;
typedef __attribute__((ext_vector_type(4))) float  f32x4;
typedef __attribute__((ext_vector_type(4))) int    i32x4;
typedef __attribute__((ext_vector_type(4))) float  float4v;

static __device__ __constant__ float NF4_LEVELS[16] = {
    -1.0f, -0.6961928009986877f, -0.5250730514526367f, -0.39491748809814453f,
    -0.28444138169288635f, -0.18477343022823334f, -0.09105003625154495f, 0.0f,
    0.07958029955625534f, 0.16093020141124725f, 0.24611230194568634f,
    0.33791524171829224f, 0.44070982933044434f, 0.5626170039176941f,
    0.7229568362236023f, 1.0f};

// ---------------------------------------------------------------------------
// Prelude (64 blocks): A-fragment streams in MFMA order:
//   frag[st][kb][lane] (16B) = x[st*16+(lane&15)][kb*32+(lane>>4)*8..+8) bf16
// ---------------------------------------------------------------------------
__global__ void prelude_kernel(const float* __restrict__ x,
                               unsigned short* __restrict__ frag) {
    int T  = blockIdx.x * 256 + threadIdx.x;
    int st = T >> 13;
    int kb = (T >> 6) & 127;
    int l  = T & 63;
    int row = st * 16 + (l & 15);
    int k0  = kb * 32 + (l >> 4) * 8;
    const float* src = x + (size_t)row * IN_F + k0;
    unsigned w[4];
    #pragma unroll
    for (int e = 0; e < 4; ++e) {
        unsigned lo = __builtin_bit_cast(unsigned short, __float2bfloat16(src[2 * e]));
        unsigned hi = __builtin_bit_cast(unsigned short, __float2bfloat16(src[2 * e + 1]));
        w[e] = lo | (hi << 16);
    }
    i32x4 v = { (int)w[0], (int)w[1], (int)w[2], (int)w[3] };
    *reinterpret_cast<i32x4*>(frag + ((size_t)st * 8192 + kb * 64 + l) * 8) = v;
}

// ---------------------------------------------------------------------------
// Main: grid 688, 256 thr (4 waves), BARRIER-FREE K-loop.
// Block = 16 out-rows x full K=4096; wave w owns k [w*1024,+1024) as 2 units
// of 512 k. Everything a wave needs is wave-private:
//   - tabu copy      lds[wave*256 + e]                    (1KB/wave)
//   - code buffers   lds[1024 + (wave*2+u)*1024 + ...]    (2 x 4KB/wave)
//   - scales         scw[8] in registers
// => no __syncthreads until the single cross-wave reduce at the end; the
// compiler's vmcnt(0)-before-barrier drain (the structural stall of R5-R12)
// is gone: unit-1 loads issue during unit-0 compute and stay in flight.
//
// Staging: per unit, 16 rows; one row = 256 consecutive int32 = one 1KB
//   wave-load; compact 4 int32 -> 1 code dword (lane j covers unit-k [8j,8j+8)).
//   Store at (row*64 + p(j)) ^ ((row&7)<<2), p(j)=(j&0x30)|((j&3)<<2)|((j>>2)&3)
//   -> reader ds_read_b128 at (col*64 + grp*16 + g*4) ^ ((col&7)<<2) yields
//   k-steps t=0..3 of group grp. Writes 2 lanes/bank, reads ~2-way (free).
// Epilogue: one barrier, cross-wave (K) sum from aliased red regions, + bias,
// direct store. No atomics anywhere.
// ---------------------------------------------------------------------------
__global__ __launch_bounds__(256, 3) void nf4_gemm_kernel(
        const int* __restrict__ packed,
        const float* __restrict__ scales,
        const float* __restrict__ bias,
        const unsigned short* __restrict__ frag,
        float* __restrict__ out)
{
    __shared__ unsigned lds[9216];   // 36KB: 4x256 tabu | 8x1024 code dwords

    const int tid  = threadIdx.x;
    const int wave = tid >> 6;
    const int lane = tid & 63;
    const int col  = lane & 15;
    const int g    = lane >> 4;

    const int n0 = blockIdx.x * NTILE;

    // ---- wave-private tabu (no barrier needed) ----
    #pragma unroll
    for (int q = 0; q < 4; ++q) {
        int e = q * 64 + lane;
        unsigned lo = __builtin_bit_cast(unsigned short, __float2bfloat16(NF4_LEVELS[e & 15]));
        unsigned hi = __builtin_bit_cast(unsigned short, __float2bfloat16(NF4_LEVELS[(e >> 4) & 15]));
        lds[wave * 256 + e] = lo | (hi << 16);
    }

    // ---- scales in registers: this lane's row = n0+col, groups wave*8..+8 ----
    float scw[8];
    {
        const float* sp = scales + (size_t)(n0 + col) * 32 + wave * 8;
        float4v sv0 = *reinterpret_cast<const float4v*>(sp);
        float4v sv1 = *reinterpret_cast<const float4v*>(sp + 4);
        scw[0]=sv0.x; scw[1]=sv0.y; scw[2]=sv0.z; scw[3]=sv0.w;
        scw[4]=sv1.x; scw[5]=sv1.y; scw[6]=sv1.z; scw[7]=sv1.w;
    }

    const int dperm = (lane & 0x30) | ((lane & 3) << 2) | ((lane >> 2) & 3);

    // batch = 8 rows (r0 = 0 or 8) of unit u; one contiguous 1KB load per row
    #define PLOAD(u, r0, sr)                                                   \
        _Pragma("unroll")                                                      \
        for (int ii = 0; ii < 8; ++ii) {                                       \
            sr[ii] = *reinterpret_cast<const i32x4*>(                          \
                packed + (size_t)(n0 + (r0) + ii) * (IN_F / 2)                 \
                       + wave * 512 + (u) * 256 + lane * 4);                   \
        }

    #define PWRITE(u, r0, sr)                                                  \
        _Pragma("unroll")                                                      \
        for (int ii = 0; ii < 8; ++ii) {                                       \
            int row = (r0) + ii;                                               \
            unsigned v = ((unsigned)(sr[ii][0] & 255))                         \
                       | ((unsigned)(sr[ii][1] & 255) << 8)                    \
                       | ((unsigned)(sr[ii][2] & 255) << 16)                   \
                       | ((unsigned)(sr[ii][3] & 255) << 24);                  \
            lds[1024 + (wave * 2 + (u)) * 1024                                 \
                + ((row * 64 + dperm) ^ ((row & 7) << 2))] = v;                \
        }

    f32x4 acc0 = (f32x4){0.f,0.f,0.f,0.f};   // batch 0-15
    f32x4 acc1 = (f32x4){0.f,0.f,0.f,0.f};   // batch 16-31

    const unsigned short* f0 = frag;
    const unsigned short* f1 = frag + 65536;

    // one group = 128 k of unit u: 1 b128 code read + 8 A-loads + 8 MFMA
    #define COMPUTE_GRP(u, grp)                                                \
    {                                                                          \
        i32x4 cd = *reinterpret_cast<const i32x4*>(                            \
            &lds[1024 + (wave * 2 + (u)) * 1024                                \
                 + ((col * 64 + (grp) * 16 + g * 4) ^ ((col & 7) << 2))]);     \
        bf16x8 A0[4], A1[4];                                                   \
        _Pragma("unroll")                                                      \
        for (int t = 0; t < 4; ++t) {                                          \
            int kb = wave * 32 + (u) * 16 + (grp) * 4 + t;                     \
            A0[t] = *reinterpret_cast<const bf16x8*>(f0 + ((size_t)kb * 64 + lane) * 8); \
            A1[t] = *reinterpret_cast<const bf16x8*>(f1 + ((size_t)kb * 64 + lane) * 8); \
        }                                                                      \
        f32x4 t0 = (f32x4){0.f,0.f,0.f,0.f};                                   \
        f32x4 t1 = (f32x4){0.f,0.f,0.f,0.f};                                   \
        _Pragma("unroll")                                                      \
        for (int t = 0; t < 4; ++t) {                                          \
            unsigned code = (unsigned)cd[t];                                   \
            i32x4 bu;                                                          \
            bu[0] = (int)lds[wave * 256 + (code & 255u)];                      \
            bu[1] = (int)lds[wave * 256 + ((code >> 8) & 255u)];               \
            bu[2] = (int)lds[wave * 256 + ((code >> 16) & 255u)];              \
            bu[3] = (int)lds[wave * 256 + (code >> 24)];                       \
            bf16x8 bf = __builtin_bit_cast(bf16x8, bu);                        \
            t0 = __builtin_amdgcn_mfma_f32_16x16x32_bf16(A0[t], bf, t0, 0, 0, 0); \
            t1 = __builtin_amdgcn_mfma_f32_16x16x32_bf16(A1[t], bf, t1, 0, 0, 0); \
        }                                                                      \
        const float sc = scw[(u) * 4 + (grp)];                                 \
        _Pragma("unroll")                                                      \
        for (int j = 0; j < 4; ++j) {                                          \
            acc0[j] = fmaf(sc, t0[j], acc0[j]);                                \
            acc1[j] = fmaf(sc, t1[j], acc1[j]);                                \
        }                                                                      \
    }

    // ---- barrier-free pipeline ----
    i32x4 sa[8], sb[8];
    PLOAD(0, 0, sa)
    PLOAD(0, 8, sb)
    PWRITE(0, 0, sa)             // waits only its own vmcnt (sb stays in flight)
    PWRITE(0, 8, sb)

    COMPUTE_GRP(0, 0)
    PLOAD(1, 0, sa)              // unit-1 loads fly under unit-0 compute
    COMPUTE_GRP(0, 1)
    PLOAD(1, 8, sb)
    COMPUTE_GRP(0, 2)
    COMPUTE_GRP(0, 3)

    PWRITE(1, 0, sa)
    PWRITE(1, 8, sb)
    COMPUTE_GRP(1, 0)
    COMPUTE_GRP(1, 1)
    COMPUTE_GRP(1, 2)
    COMPUTE_GRP(1, 3)

    // ---- epilogue: red aliases wave's unit-0 code buffer (own reads done) ----
    float* red = (float*)&lds[1024 + wave * 2048];
    #pragma unroll
    for (int j = 0; j < 4; ++j) {
        red[(0 * 4 + j) * 64 + g * 16 + col] = acc0[j];
        red[(1 * 4 + j) * 64 + g * 16 + col] = acc1[j];
    }
    __syncthreads();             // the ONE barrier

    #pragma unroll
    for (int p = 0; p < 2; ++p) {
        int idx = p * 256 + tid;             // [0,512)
        int b   = idx >> 4;                  // batch row
        int c   = idx & 15;                  // out-feature local
        int h   = b >> 4;
        int r   = b & 15;
        int j   = r & 3;
        int g2  = r >> 2;
        int slot = (h * 4 + j) * 64 + g2 * 16 + c;
        const float* rbase = (const float*)&lds[1024];
        float s = rbase[slot] + rbase[2048 / 4 * 4 + slot]   // wave1: +2048 dwords
                + rbase[4096 + slot] + rbase[6144 + slot];
        out[(size_t)b * OUT_F + n0 + c] = s + bias[n0 + c];
    }
}

// ---------------------------------------------------------------------------
extern "C" void kernel_launch(void* const* d_in, const int* in_sizes, int n_in,
                              void* d_out, int out_size, void* d_ws, size_t ws_size,
                              hipStream_t stream) {
    const float* x      = (const float*)d_in[0];
    const int*   packed = (const int*)d_in[1];
    const float* scales = (const float*)d_in[2];
    const float* bias   = (const float*)d_in[3];
    float* out = (float*)d_out;

    unsigned short* frag = (unsigned short*)d_ws;   // 256 KB

    prelude_kernel<<<64, 256, 0, stream>>>(x, frag);
    nf4_gemm_kernel<<<GRID_N, 256, 0, stream>>>(packed, scales, bias, frag, out);
}